// Round 1
// baseline (355.688 us; speedup 1.0000x reference)
//
#include <hip/hip_runtime.h>
#include <hip/hip_bf16.h>

#define H   20
#define H2  40
#define T   512
#define D   128
#define NN  1024
#define K   (T*D)   // 65536

// ---------------------------------------------------------------------------
// Setup kernel: the reference recurrence is rank-1 (state collapses to the
// scalar h[:, H] each step), so the whole scan reduces to
//   out_n = c0 + sum_{t,d} W[t,d] * x[n,t,d]
// This kernel computes W (T*D floats), c0, and tmin (first t with nonzero
// coefficients; geometric decay g^k underflows quickly) into d_ws.
// ---------------------------------------------------------------------------
__global__ __launch_bounds__(256) void setup_kernel(
    const float* __restrict__ C_w,    // (H2, D)
    const float* __restrict__ B_w,    // (1, H2)
    const float* __restrict__ refl,   // (2, H2)
    const float* __restrict__ theta,  // (3, H)
    const float* __restrict__ mu0,    // (H,)
    float* __restrict__ Wout,         // K floats
    float* __restrict__ extra)        // [0]=c0 (float), [1]=tmin (int bits)
{
    __shared__ double twr[H], twi[H];                  // e^{-2*pi*i*m/H}
    __shared__ double c0t[H], s0t[H], c1t[H], s1t[H], c2t[H], s2t[H];
    __shared__ double v0r_s[H], v0i_s[H], v1r_s[H], v1i_s[H];
    __shared__ double scale0_s, scale1_s;
    __shared__ double a_s[H2];
    __shared__ double fr_s[H], fi_s[H];
    __shared__ double sr_s, si_s;
    __shared__ double w_s[H2];
    __shared__ double g_s, Bw_s;
    __shared__ double lgabs_s;
    __shared__ int gneg_s, gzero_s;
    __shared__ double alpha_s[D], beta_s[D];
    __shared__ double pw_s[T];                         // pw[t] = g^{T-2-t}
    __shared__ int tmin_s;
    __shared__ double c0_s;

    const double PI = 3.141592653589793238462643383279502884;
    const int tid = threadIdx.x;
    const double invsH = 1.0 / sqrt((double)H);

    if (tid < H) {
        double ang = -2.0 * PI * (double)tid / (double)H;
        twr[tid] = cos(ang); twi[tid] = sin(ang);
        double t0 = theta[tid], t1 = theta[H + tid], t2 = theta[2*H + tid];
        c0t[tid] = cos(t0); s0t[tid] = sin(t0);
        c1t[tid] = cos(t1); s1t[tid] = sin(t1);
        c2t[tid] = cos(t2); s2t[tid] = sin(t2);
        v0r_s[tid] = refl[tid];        v0i_s[tid] = refl[H + tid];
        v1r_s[tid] = refl[H2 + tid];   v1i_s[tid] = refl[H2 + H + tid];
    }
    if (tid == 0) {
        double vv0 = 0.0, vv1 = 0.0;
        for (int j = 0; j < H2; j++) {
            double r0 = refl[j], r1 = refl[H2 + j];
            vv0 += r0 * r0; vv1 += r1 * r1;
        }
        scale0_s = 2.0 / vv0; scale1_s = 2.0 / vv1;
    }
    __syncthreads();

    // a_j = Im( [R0 * F * D0 * e_j]_0 ), i.e. element H of the real repr.
    // D0*e_j is a single complex entry at p=j%H: e^{i th0_p} (j<H) or i*e^{i th0_p}.
    if (tid < H2) {
        int j = tid, p = j % H;
        double vr, vi;
        if (j < H) { vr = c0t[p]; vi = s0t[p]; }
        else       { vr = -s0t[p]; vi = c0t[p]; }
        double sr = 0.0, si = 0.0;
        for (int n = 0; n < H; n++) {
            int m = (n * p) % H;
            double wr = twr[m], wi = twi[m];
            double fr = vr * wr - vi * wi;      // (F x)_n * sqrt(H)
            double fi = vr * wi + vi * wr;
            sr += v0r_s[n] * fr - v0i_s[n] * fi;  // s1 = xr.vr - xi.vi
            si += v0r_s[n] * fi + v0i_s[n] * fr;  // s2 = xr.vi + xi.vr
        }
        sr *= invsH; si *= invsH;
        double f0i = invsH * vi;                // Im((F x)_0)
        a_s[j] = f0i - scale0_s * (si * v0r_s[0] - sr * v0i_s[0]);
    }
    // f = ifft(u)/sqrt(H), u_j = (cos-sin) + i(cos+sin) of theta1
    if (tid >= 64 && tid < 64 + H) {
        int n = tid - 64;
        double accr = 0.0, acci = 0.0;
        for (int k = 0; k < H; k++) {
            int m = (k * n) % H;
            double wr = twr[m], wi = -twi[m];   // e^{+2*pi*i*k*n/H}
            double urk = c1t[k] - s1t[k], uik = c1t[k] + s1t[k];
            accr += urk * wr - uik * wi;
            acci += urk * wi + uik * wr;
        }
        double sc = invsH / (double)H;
        fr_s[n] = accr * sc; fi_s[n] = acci * sc;
    }
    __syncthreads();

    if (tid == 0) {
        double sr = 0.0, si = 0.0;
        for (int n = 0; n < H; n++) {
            sr += v1r_s[n] * fr_s[n] - v1i_s[n] * fi_s[n];
            si += v1r_s[n] * fi_s[n] + v1i_s[n] * fr_s[n];
        }
        sr_s = sr; si_s = si;
    }
    __syncthreads();

    // w = D2 * R1 * f  (real representation)
    if (tid < H) {
        int n = tid;
        double yr = fr_s[n] - scale1_s * (sr_s * v1r_s[n] + si_s * v1i_s[n]);
        double yi = fi_s[n] - scale1_s * (si_s * v1r_s[n] - sr_s * v1i_s[n]);
        w_s[n]     = yr * c2t[n] - yi * s2t[n];
        w_s[H + n] = yi * c2t[n] + yr * s2t[n];
    }
    __syncthreads();

    if (tid == 0) {
        double g = 0.0, Bw = 0.0;
        for (int j = 0; j < H2; j++) g  += a_s[j] * w_s[j];
        for (int j = 0; j < H2; j++) Bw += (double)B_w[j] * w_s[j];
        g_s = g; Bw_s = Bw;
        gzero_s = (g == 0.0);
        gneg_s  = (g < 0.0);
        lgabs_s = (g == 0.0) ? 0.0 : log2(fabs(g));
    }
    __syncthreads();

    // pw[t] = g^{T-2-t} for t in [0, T-2]
    for (int t = tid; t < T - 1; t += blockDim.x) {
        int k = (T - 2) - t;
        double val;
        if (k == 0)          val = 1.0;
        else if (gzero_s)    val = 0.0;
        else {
            val = exp2((double)k * lgabs_s);
            if (gneg_s && (k & 1)) val = -val;
        }
        pw_s[t] = val;
    }
    // alpha_d = sum_j a_j C_w[j,d];  beta_d = sum_j B_j C_w[j,d]
    if (tid < D) {
        double al = 0.0, be = 0.0;
        for (int j = 0; j < H2; j++) {
            double cw = C_w[j * D + tid];
            al += a_s[j] * cw;
            be += (double)B_w[j] * cw;
        }
        alpha_s[tid] = al; beta_s[tid] = be;
    }
    __syncthreads();

    if (tid == 0) {
        double amax = 0.0;
        for (int d2 = 0; d2 < D; d2++) amax = fmax(amax, fabs(alpha_s[d2]));
        double absBw = fabs(Bw_s);
        int tmin = T - 1;
        for (int t = 0; t < T - 1; t++) {
            if (absBw * fabs(pw_s[t]) * amax >= 1e-20) { tmin = t; break; }
        }
        tmin_s = tmin;
        double s0 = 0.0;
        for (int j = 0; j < H; j++) s0 += (a_s[j] - a_s[H + j]) * (double)mu0[j];
        c0_s = Bw_s * g_s * pw_s[0] * s0;   // Bw * g^{T-1} * s0
    }
    __syncthreads();

    // W[t,d]
    for (int idx = tid; idx < K; idx += blockDim.x) {
        int t = idx >> 7, d2 = idx & (D - 1);
        double val = (t == T - 1) ? beta_s[d2] : Bw_s * pw_s[t] * alpha_s[d2];
        Wout[idx] = (float)val;
    }
    if (tid == 0) {
        extra[0] = (float)c0_s;
        ((int*)extra)[1] = tmin_s;
    }
}

// ---------------------------------------------------------------------------
// Dot kernel: one block per row n.  out[n] = c0 + dot(x[n, tmin*D:], W[tmin*D:])
// ---------------------------------------------------------------------------
__global__ __launch_bounds__(512) void dot_kernel(
    const float* __restrict__ x,      // (NN, K)
    const float* __restrict__ Wv,     // K floats
    const float* __restrict__ extra,  // [c0, tmin]
    float* __restrict__ out)          // NN floats
{
    const int n = blockIdx.x;
    const int tmin = ((const int*)extra)[1];
    const int i0 = tmin << 5;                 // tmin * D / 4 float4s
    const float4* xp = (const float4*)(x + (size_t)n * K);
    const float4* wp = (const float4*)Wv;

    float acc = 0.f;
    for (int i = i0 + threadIdx.x; i < (K >> 2); i += blockDim.x) {
        float4 a = xp[i];
        float4 b = wp[i];
        acc += a.x * b.x + a.y * b.y + a.z * b.z + a.w * b.w;
    }
    // wave reduction (64 lanes)
    for (int off = 32; off > 0; off >>= 1) acc += __shfl_down(acc, off, 64);

    __shared__ float wsum[8];
    const int lane = threadIdx.x & 63, wid = threadIdx.x >> 6;
    if (lane == 0) wsum[wid] = acc;
    __syncthreads();
    if (threadIdx.x == 0) {
        float tot = extra[0];
        const int nw = blockDim.x >> 6;
        for (int wv = 0; wv < nw; wv++) tot += wsum[wv];
        out[n] = tot;
    }
}

extern "C" void kernel_launch(void* const* d_in, const int* in_sizes, int n_in,
                              void* d_out, int out_size, void* d_ws, size_t ws_size,
                              hipStream_t stream) {
    const float* inputs = (const float*)d_in[0];  // (N, T, D)
    const float* C_w    = (const float*)d_in[1];  // (H2, D)
    const float* B_w    = (const float*)d_in[2];  // (1, H2)
    const float* refl   = (const float*)d_in[3];  // (2, H2)
    const float* theta  = (const float*)d_in[4];  // (3, H)
    const float* mu0    = (const float*)d_in[5];  // (H,)
    float* out = (float*)d_out;

    float* Wv    = (float*)d_ws;       // K floats
    float* extra = Wv + K;             // 2 floats

    setup_kernel<<<1, 256, 0, stream>>>(C_w, B_w, refl, theta, mu0, Wv, extra);
    dot_kernel<<<NN, 512, 0, stream>>>(inputs, Wv, extra, out);
}

// Round 2
// 339.090 us; speedup vs baseline: 1.0489x; 1.0489x over previous
//
#include <hip/hip_runtime.h>
#include <hip/hip_bf16.h>

#define H   20
#define H2  40
#define T   512
#define D   128
#define NN  1024
#define K   (T*D)   // 65536

// ws layout (floats):
//   [0 .. T-1]      coef[t]  (coef[T-1] == 1.0, used with beta)
//   [T .. T+127]    alpha[d]
//   [T+128..T+255]  beta[d]
//   [T+256]         c0
//   [T+257]         tmin (int bits)
#define WS_COEF  0
#define WS_ALPHA T
#define WS_BETA  (T + D)
#define WS_C0    (T + 2*D)
#define WS_TMIN  (T + 2*D + 1)

// ---------------------------------------------------------------------------
// The reference recurrence is rank-1 (state collapses to the scalar h[:, H]
// each step), so the whole scan reduces to
//   out_n = c0 + sum_d beta_d x[n,T-1,d] + sum_{t<T-1,d} Bw g^{T-2-t} alpha_d x[n,t,d]
// Setup computes the tiny coefficient set in double precision.
// ---------------------------------------------------------------------------
__global__ __launch_bounds__(256) void setup_kernel(
    const float* __restrict__ C_w,    // (H2, D)
    const float* __restrict__ B_w,    // (1, H2)
    const float* __restrict__ refl,   // (2, H2)
    const float* __restrict__ theta,  // (3, H)
    const float* __restrict__ mu0,    // (H,)
    float* __restrict__ ws)
{
    __shared__ double twr[H], twi[H];                  // e^{-2*pi*i*m/H}
    __shared__ double c0t[H], s0t[H], c1t[H], s1t[H], c2t[H], s2t[H];
    __shared__ double v0r_s[H], v0i_s[H], v1r_s[H], v1i_s[H];
    __shared__ double scale0_s, scale1_s;
    __shared__ double a_s[H2];
    __shared__ double fr_s[H], fi_s[H];
    __shared__ double sr_s, si_s;
    __shared__ double w_s[H2];
    __shared__ double g_s, Bw_s;
    __shared__ double lgabs_s;
    __shared__ int gneg_s, gzero_s;
    __shared__ double alpha_s[D];
    __shared__ double pw_s[T];                         // pw[t] = g^{T-2-t}
    __shared__ double amax_s;

    const double PI = 3.141592653589793238462643383279502884;
    const int tid = threadIdx.x;
    const double invsH = 1.0 / sqrt((double)H);

    if (tid < H) {
        double ang = -2.0 * PI * (double)tid / (double)H;
        twr[tid] = cos(ang); twi[tid] = sin(ang);
        double t0 = theta[tid], t1 = theta[H + tid], t2 = theta[2*H + tid];
        c0t[tid] = cos(t0); s0t[tid] = sin(t0);
        c1t[tid] = cos(t1); s1t[tid] = sin(t1);
        c2t[tid] = cos(t2); s2t[tid] = sin(t2);
        v0r_s[tid] = refl[tid];        v0i_s[tid] = refl[H + tid];
        v1r_s[tid] = refl[H2 + tid];   v1i_s[tid] = refl[H2 + H + tid];
    }
    if (tid == 0) {
        double vv0 = 0.0, vv1 = 0.0;
        for (int j = 0; j < H2; j++) {
            double r0 = refl[j], r1 = refl[H2 + j];
            vv0 += r0 * r0; vv1 += r1 * r1;
        }
        scale0_s = 2.0 / vv0; scale1_s = 2.0 / vv1;
    }
    __syncthreads();

    // a_j = element H of (R0 * F * D0 * e_j) in the real representation.
    if (tid < H2) {
        int j = tid, p = j % H;
        double vr, vi;
        if (j < H) { vr = c0t[p]; vi = s0t[p]; }
        else       { vr = -s0t[p]; vi = c0t[p]; }
        double sr = 0.0, si = 0.0;
        for (int n = 0; n < H; n++) {
            int m = (n * p) % H;
            double wr = twr[m], wi = twi[m];
            double fr = vr * wr - vi * wi;      // (F x)_n * sqrt(H)
            double fi = vr * wi + vi * wr;
            sr += v0r_s[n] * fr - v0i_s[n] * fi;
            si += v0r_s[n] * fi + v0i_s[n] * fr;
        }
        sr *= invsH; si *= invsH;
        double f0i = invsH * vi;                // Im((F x)_0)
        a_s[j] = f0i - scale0_s * (si * v0r_s[0] - sr * v0i_s[0]);
    }
    // f = ifft(u)/sqrt(H), u_k = (cos-sin) + i(cos+sin) of theta1
    if (tid >= 64 && tid < 64 + H) {
        int n = tid - 64;
        double accr = 0.0, acci = 0.0;
        for (int k = 0; k < H; k++) {
            int m = (k * n) % H;
            double wr = twr[m], wi = -twi[m];   // e^{+2*pi*i*k*n/H}
            double urk = c1t[k] - s1t[k], uik = c1t[k] + s1t[k];
            accr += urk * wr - uik * wi;
            acci += urk * wi + uik * wr;
        }
        double sc = invsH / (double)H;
        fr_s[n] = accr * sc; fi_s[n] = acci * sc;
    }
    __syncthreads();

    if (tid == 0) {
        double sr = 0.0, si = 0.0;
        for (int n = 0; n < H; n++) {
            sr += v1r_s[n] * fr_s[n] - v1i_s[n] * fi_s[n];
            si += v1r_s[n] * fi_s[n] + v1i_s[n] * fr_s[n];
        }
        sr_s = sr; si_s = si;
    }
    __syncthreads();

    // w = D2 * R1 * f  (real representation)
    if (tid < H) {
        int n = tid;
        double yr = fr_s[n] - scale1_s * (sr_s * v1r_s[n] + si_s * v1i_s[n]);
        double yi = fi_s[n] - scale1_s * (si_s * v1r_s[n] - sr_s * v1i_s[n]);
        w_s[n]     = yr * c2t[n] - yi * s2t[n];
        w_s[H + n] = yi * c2t[n] + yr * s2t[n];
    }
    __syncthreads();

    if (tid == 0) {
        double g = 0.0, Bw = 0.0;
        for (int j = 0; j < H2; j++) g  += a_s[j] * w_s[j];
        for (int j = 0; j < H2; j++) Bw += (double)B_w[j] * w_s[j];
        g_s = g; Bw_s = Bw;
        gzero_s = (g == 0.0);
        gneg_s  = (g < 0.0);
        lgabs_s = (g == 0.0) ? 0.0 : log2(fabs(g));
    }
    __syncthreads();

    // pw[t] = g^{T-2-t} for t in [0, T-2]
    for (int t = tid; t < T - 1; t += blockDim.x) {
        int k = (T - 2) - t;
        double val;
        if (k == 0)          val = 1.0;
        else if (gzero_s)    val = 0.0;
        else {
            val = exp2((double)k * lgabs_s);
            if (gneg_s && (k & 1)) val = -val;
        }
        pw_s[t] = val;
        ws[WS_COEF + t] = (float)(Bw_s * val);
    }
    if (tid == 0) ws[WS_COEF + T - 1] = 1.0f;

    // alpha_d = sum_j a_j C_w[j,d];  beta_d = sum_j B_j C_w[j,d]
    if (tid < D) {
        double al = 0.0, be = 0.0;
        for (int j = 0; j < H2; j++) {
            double cw = C_w[j * D + tid];
            al += a_s[j] * cw;
            be += (double)B_w[j] * cw;
        }
        alpha_s[tid] = al;
        ws[WS_ALPHA + tid] = (float)al;
        ws[WS_BETA  + tid] = (float)be;
    }
    __syncthreads();

    if (tid == 0) {
        double amax = 0.0;
        for (int d2 = 0; d2 < D; d2++) amax = fmax(amax, fabs(alpha_s[d2]));
        amax_s = amax;
        double absBw = fabs(Bw_s);
        int tmin = T - 1;
        for (int t = 0; t < T - 1; t++) {
            if (absBw * fabs(pw_s[t]) * amax >= 1e-20) { tmin = t; break; }
        }
        double s0 = 0.0;
        for (int j = 0; j < H; j++) s0 += (a_s[j] - a_s[H + j]) * (double)mu0[j];
        ws[WS_C0] = (float)(Bw_s * g_s * pw_s[0] * s0);   // Bw * g^(T-1) * s0
        ((int*)ws)[WS_TMIN] = tmin;
    }
}

// ---------------------------------------------------------------------------
// Dot kernel: one block per row n.
//   out[n] = c0 + sum_{i >= tmin*32} coef[t(i)] * dot(x4[n,i], w4[i&31])
// ---------------------------------------------------------------------------
__global__ __launch_bounds__(256) void dot_kernel(
    const float* __restrict__ x,      // (NN, K)
    const float* __restrict__ ws,
    float* __restrict__ out)          // NN floats
{
    __shared__ float coef_s[T];
    __shared__ float4 a4_s[D/4], b4_s[D/4];
    __shared__ float wsum[4];

    const int tid = threadIdx.x;
    // stage coefficients into LDS
    coef_s[tid]       = ws[WS_COEF + tid];
    coef_s[256 + tid] = ws[WS_COEF + 256 + tid];
    if (tid < D/4)            a4_s[tid]        = ((const float4*)(ws + WS_ALPHA))[tid];
    else if (tid < D/2)       b4_s[tid - D/4]  = ((const float4*)(ws + WS_BETA))[tid - D/4];
    const int tmin = ((const int*)ws)[WS_TMIN];
    __syncthreads();

    const int n = blockIdx.x;
    const int i0 = tmin << 5;                 // tmin * D/4
    const float4* xp = (const float4*)(x + (size_t)n * K);

    float acc = 0.f;
    for (int i = i0 + tid; i < (K >> 2); i += 256) {
        int t = i >> 5, q = i & 31;
        float4 x4 = xp[i];
        float4 w4 = (t == T - 1) ? b4_s[q] : a4_s[q];
        float  c  = coef_s[t];
        acc += c * (x4.x * w4.x + x4.y * w4.y + x4.z * w4.z + x4.w * w4.w);
    }
    // wave reduction (64 lanes)
    for (int off = 32; off > 0; off >>= 1) acc += __shfl_down(acc, off, 64);

    const int lane = tid & 63, wid = tid >> 6;
    if (lane == 0) wsum[wid] = acc;
    __syncthreads();
    if (tid == 0) {
        float tot = ws[WS_C0];
        for (int wv = 0; wv < 4; wv++) tot += wsum[wv];
        out[n] = tot;
    }
}

extern "C" void kernel_launch(void* const* d_in, const int* in_sizes, int n_in,
                              void* d_out, int out_size, void* d_ws, size_t ws_size,
                              hipStream_t stream) {
    const float* inputs = (const float*)d_in[0];  // (N, T, D)
    const float* C_w    = (const float*)d_in[1];  // (H2, D)
    const float* B_w    = (const float*)d_in[2];  // (1, H2)
    const float* refl   = (const float*)d_in[3];  // (2, H2)
    const float* theta  = (const float*)d_in[4];  // (3, H)
    const float* mu0    = (const float*)d_in[5];  // (H,)
    float* out = (float*)d_out;
    float* ws  = (float*)d_ws;

    setup_kernel<<<1, 256, 0, stream>>>(C_w, B_w, refl, theta, mu0, ws);
    dot_kernel<<<NN, 256, 0, stream>>>(inputs, ws, out);
}

// Round 3
// 312.472 us; speedup vs baseline: 1.1383x; 1.0852x over previous
//
#include <hip/hip_runtime.h>
#include <hip/hip_bf16.h>

#define H   20
#define H2  40
#define T   512
#define D   128
#define NN  1024
#define K   (T*D)   // 65536

// Compile-time tail start. |g| <= ||a||*||w|| = sqrt(2/H) = 0.31623 exactly
// (a is one row of an orthogonal map; w is the image of the unit scalar
// through unitary ops with a 1/sqrt(2H)*sqrt(2) net fft/ifft scaling), so
// log2|g| <= -1.66 and terms older than 48 steps are < 1e-23 — far below
// fp32 output resolution. 49-step tail + final beta row.
#define TMIN 463
#define NT   (T - TMIN)   // 49 coef entries (t = TMIN .. T-1)

// ---------------------------------------------------------------------------
// The reference recurrence is rank-1 (state collapses to the scalar h[:, H]
// each step), so the whole scan reduces to
//   out_n = c0 + sum_d beta_d x[n,T-1,d] + sum_{t<T-1,d} Bw g^{T-2-t} alpha_d x[n,t,d]
// Every block redundantly computes the tiny coefficient set in double
// precision in LDS (hides setup latency across blocks; no second launch),
// then does a coalesced float4 dot over its row's tail.
// ---------------------------------------------------------------------------
__global__ __launch_bounds__(256) void urnn_fused_kernel(
    const float* __restrict__ x,      // (NN, T, D)
    const float* __restrict__ C_w,    // (H2, D)
    const float* __restrict__ B_w,    // (1, H2)
    const float* __restrict__ refl,   // (2, H2)
    const float* __restrict__ theta,  // (3, H)
    const float* __restrict__ mu0,    // (H,)
    float* __restrict__ out)          // NN floats
{
    __shared__ double twr[H], twi[H];                  // e^{-2*pi*i*m/H}
    __shared__ double c0t[H], s0t[H], c1t[H], s1t[H], c2t[H], s2t[H];
    __shared__ double v0r_s[H], v0i_s[H], v1r_s[H], v1i_s[H];
    __shared__ double scale0_s, scale1_s;
    __shared__ double a_s[H2];
    __shared__ double fr_s[H], fi_s[H];
    __shared__ double srd_s, sid_s;
    __shared__ double w_s[H2];
    __shared__ double g_s, Bw_s, lgabs_s;
    __shared__ int gneg_s, gzero_s;
    __shared__ float coef_s[NT];
    __shared__ float4 a4_s[D/4], b4_s[D/4];
    __shared__ float c0f_s;
    __shared__ float wsum[4];

    const double PI = 3.141592653589793238462643383279502884;
    const int tid = threadIdx.x;
    const double invsH = 1.0 / sqrt((double)H);

    // ---- phase A: twiddles, per-theta trig, reflection vectors ----
    if (tid < H) {
        double ang = -2.0 * PI * (double)tid / (double)H;
        twr[tid] = cos(ang); twi[tid] = sin(ang);
        double t0 = theta[tid], t1 = theta[H + tid], t2 = theta[2*H + tid];
        c0t[tid] = cos(t0); s0t[tid] = sin(t0);
        c1t[tid] = cos(t1); s1t[tid] = sin(t1);
        c2t[tid] = cos(t2); s2t[tid] = sin(t2);
        v0r_s[tid] = refl[tid];        v0i_s[tid] = refl[H + tid];
        v1r_s[tid] = refl[H2 + tid];   v1i_s[tid] = refl[H2 + H + tid];
    }
    if (tid == 64) {
        double vv0 = 0.0, vv1 = 0.0;
        for (int j = 0; j < H2; j++) {
            double r0 = refl[j], r1 = refl[H2 + j];
            vv0 += r0 * r0; vv1 += r1 * r1;
        }
        scale0_s = 2.0 / vv0; scale1_s = 2.0 / vv1;
    }
    __syncthreads();

    // ---- phase B: a_j = element H of (R0 * F * D0 * e_j), and f = D2-input ----
    if (tid < H2) {
        int j = tid, p = j % H;
        double vr, vi;
        if (j < H) { vr = c0t[p]; vi = s0t[p]; }
        else       { vr = -s0t[p]; vi = c0t[p]; }
        double sr = 0.0, si = 0.0;
        for (int n = 0; n < H; n++) {
            int m = (n * p) % H;
            double wr = twr[m], wi = twi[m];
            double fr = vr * wr - vi * wi;      // (F x)_n * sqrt(H)
            double fi = vr * wi + vi * wr;
            sr += v0r_s[n] * fr - v0i_s[n] * fi;
            si += v0r_s[n] * fi + v0i_s[n] * fr;
        }
        sr *= invsH; si *= invsH;
        double f0i = invsH * vi;                // Im((F x)_0)
        a_s[j] = f0i - scale0_s * (si * v0r_s[0] - sr * v0i_s[0]);
    }
    // f = ifft(u)/sqrt(H), u_k = (cos-sin) + i(cos+sin) of theta1
    if (tid >= 64 && tid < 64 + H) {
        int n = tid - 64;
        double accr = 0.0, acci = 0.0;
        for (int k = 0; k < H; k++) {
            int m = (k * n) % H;
            double wr = twr[m], wi = -twi[m];   // e^{+2*pi*i*k*n/H}
            double urk = c1t[k] - s1t[k], uik = c1t[k] + s1t[k];
            accr += urk * wr - uik * wi;
            acci += urk * wi + uik * wr;
        }
        double sc = invsH / (double)H;
        fr_s[n] = accr * sc; fi_s[n] = acci * sc;
    }
    __syncthreads();

    // ---- phase C: reflection inner product (tid 0) + alpha/beta (tid>=128) ----
    if (tid == 0) {
        double sr = 0.0, si = 0.0;
        for (int n = 0; n < H; n++) {
            sr += v1r_s[n] * fr_s[n] - v1i_s[n] * fi_s[n];
            si += v1r_s[n] * fi_s[n] + v1i_s[n] * fr_s[n];
        }
        srd_s = sr; sid_s = si;
    }
    if (tid >= 128) {
        int d = tid - 128;
        double al = 0.0, be = 0.0;
        for (int j = 0; j < H2; j++) {
            double cw = C_w[j * D + d];
            al += a_s[j] * cw;
            be += (double)B_w[j] * cw;
        }
        ((float*)a4_s)[d] = (float)al;
        ((float*)b4_s)[d] = (float)be;
    }
    __syncthreads();

    // ---- phase D: w = D2 * R1 * f ----
    if (tid < H) {
        int n = tid;
        double yr = fr_s[n] - scale1_s * (srd_s * v1r_s[n] + sid_s * v1i_s[n]);
        double yi = fi_s[n] - scale1_s * (sid_s * v1r_s[n] - srd_s * v1i_s[n]);
        w_s[n]     = yr * c2t[n] - yi * s2t[n];
        w_s[H + n] = yi * c2t[n] + yr * s2t[n];
    }
    __syncthreads();

    // ---- phase E: g, Bw, c0 ----
    if (tid == 0) {
        double g = 0.0, Bw = 0.0;
        for (int j = 0; j < H2; j++) g  += a_s[j] * w_s[j];
        for (int j = 0; j < H2; j++) Bw += (double)B_w[j] * w_s[j];
        g_s = g; Bw_s = Bw;
        gzero_s = (g == 0.0);
        gneg_s  = (g < 0.0);
        lgabs_s = (g == 0.0) ? 0.0 : log2(fabs(g));
        // c0 = Bw * g^(T-1) * (a . h0);  g^(T-1) underflows double -> 0, fine.
        double s0 = 0.0;
        for (int j = 0; j < H; j++) s0 += (a_s[j] - a_s[H + j]) * (double)mu0[j];
        double pw;
        if (g == 0.0) pw = 0.0;
        else {
            pw = exp2((double)(T - 1) * log2(fabs(g)));
            if (g < 0.0 && ((T - 1) & 1)) pw = -pw;
        }
        c0f_s = (float)(Bw * pw * s0);
    }
    __syncthreads();

    // ---- phase F: coef[t] = Bw * g^(T-2-t) for t in [TMIN, T-2]; coef[T-1]=1 ----
    if (tid < NT) {
        int t = TMIN + tid;
        int k = (T - 2) - t;              // 47..0, then -1 for t = T-1
        float c;
        if (t == T - 1) c = 1.0f;
        else {
            double val;
            if (k == 0)          val = 1.0;
            else if (gzero_s)    val = 0.0;
            else {
                val = exp2((double)k * lgabs_s);
                if (gneg_s && (k & 1)) val = -val;
            }
            c = (float)(Bw_s * val);
        }
        coef_s[tid] = c;
    }
    __syncthreads();

    // ---- dot phase: out[n] = c0 + sum_{i>=TMIN*32} coef[t] * dot(x4, w4) ----
    const int n = blockIdx.x;
    const float4* xp = (const float4*)(x + (size_t)n * K);

    float acc = 0.f;
    for (int i = (TMIN << 5) + tid; i < (K >> 2); i += 256) {
        int t = i >> 5, q = i & 31;
        float4 x4 = xp[i];
        float4 w4 = (t == T - 1) ? b4_s[q] : a4_s[q];
        float  c  = coef_s[t - TMIN];
        acc += c * (x4.x * w4.x + x4.y * w4.y + x4.z * w4.z + x4.w * w4.w);
    }
    for (int off = 32; off > 0; off >>= 1) acc += __shfl_down(acc, off, 64);

    const int lane = tid & 63, wid = tid >> 6;
    if (lane == 0) wsum[wid] = acc;
    __syncthreads();
    if (tid == 0) {
        float tot = c0f_s;
        for (int wv = 0; wv < 4; wv++) tot += wsum[wv];
        out[n] = tot;
    }
}

extern "C" void kernel_launch(void* const* d_in, const int* in_sizes, int n_in,
                              void* d_out, int out_size, void* d_ws, size_t ws_size,
                              hipStream_t stream) {
    const float* inputs = (const float*)d_in[0];  // (N, T, D)
    const float* C_w    = (const float*)d_in[1];  // (H2, D)
    const float* B_w    = (const float*)d_in[2];  // (1, H2)
    const float* refl   = (const float*)d_in[3];  // (2, H2)
    const float* theta  = (const float*)d_in[4];  // (3, H)
    const float* mu0    = (const float*)d_in[5];  // (H,)
    float* out = (float*)d_out;

    urnn_fused_kernel<<<NN, 256, 0, stream>>>(inputs, C_w, B_w, refl, theta, mu0, out);
}